// Round 1
// baseline (334.194 us; speedup 1.0000x reference)
//
#include <hip/hip_runtime.h>
#include <stdint.h>

#define NFR 256
#define HW 196
#define CH 512
#define EPS_POS 0.65f
#define EPS_NEG 0.40f
#define INV_TAU (1.0f/0.03f)
#define TEMP 0.07f

typedef __bf16 bf16x8 __attribute__((ext_vector_type(8)));
typedef float f32x4 __attribute__((ext_vector_type(4)));

typedef const __attribute__((address_space(1))) unsigned int* as1_u32p;
typedef __attribute__((address_space(3))) unsigned int* as3_u32p;
#define GLL(gp, lp) __builtin_amdgcn_global_load_lds((as1_u32p)(const void*)(gp), (as3_u32p)(void*)(lp), 16, 0, 0)

__device__ __forceinline__ float sigmoidf_(float x) {
  return 1.0f / (1.0f + __expf(-x));
}

// round-to-nearest-even f32 -> bf16 bits (inputs are finite)
__device__ __forceinline__ unsigned short f2bf(float x) {
  unsigned int u = __float_as_uint(x);
  unsigned int r = u + 0x7FFFu + ((u >> 16) & 1u);
  return (unsigned short)(r >> 16);
}

// ---------------- K1: audio L2-normalize -> bf16 [256][512] ----------------
__global__ __launch_bounds__(64) void audio_norm_k(const float* __restrict__ audio,
                                                   unsigned short* __restrict__ abf) {
  const int r = blockIdx.x;          // 0..255
  const int l = threadIdx.x;         // 0..63
  const float4* src = reinterpret_cast<const float4*>(audio + (size_t)r * CH);
  float4 a = src[l];
  float4 b = src[64 + l];
  float ss = a.x*a.x + a.y*a.y + a.z*a.z + a.w*a.w
           + b.x*b.x + b.y*b.y + b.z*b.z + b.w*b.w;
#pragma unroll
  for (int m = 1; m < 64; m <<= 1) ss += __shfl_xor(ss, m);
  float sc = rsqrtf(ss);
  ushort4 o;
  o.x = f2bf(a.x*sc); o.y = f2bf(a.y*sc); o.z = f2bf(a.z*sc); o.w = f2bf(a.w*sc);
  reinterpret_cast<ushort4*>(abf + (size_t)r * CH)[l] = o;
  o.x = f2bf(b.x*sc); o.y = f2bf(b.y*sc); o.z = f2bf(b.z*sc); o.w = f2bf(b.w*sc);
  reinterpret_cast<ushort4*>(abf + (size_t)r * CH)[64 + l] = o;
}

// ---------------- K2: frame L2-normalize -> bf16 [50176][512] ----------------
__global__ __launch_bounds__(256) void frame_norm_k(const float* __restrict__ frame,
                                                    unsigned short* __restrict__ fbf) {
  const int w = threadIdx.x >> 6;
  const int l = threadIdx.x & 63;
  const size_t r = (size_t)blockIdx.x * 4 + w;   // < 50176 (exact: 12544*4)
  const float4* src = reinterpret_cast<const float4*>(frame + r * CH);
  float4 a = src[l];
  float4 b = src[64 + l];
  float ss = a.x*a.x + a.y*a.y + a.z*a.z + a.w*a.w
           + b.x*b.x + b.y*b.y + b.z*b.z + b.w*b.w;
#pragma unroll
  for (int m = 1; m < 64; m <<= 1) ss += __shfl_xor(ss, m);
  float sc = rsqrtf(ss);
  ushort4 o;
  o.x = f2bf(a.x*sc); o.y = f2bf(a.y*sc); o.z = f2bf(a.z*sc); o.w = f2bf(a.w*sc);
  reinterpret_cast<ushort4*>(fbf + r * CH)[l] = o;
  o.x = f2bf(b.x*sc); o.y = f2bf(b.y*sc); o.z = f2bf(b.z*sc); o.w = f2bf(b.w*sc);
  reinterpret_cast<ushort4*>(fbf + r * CH)[64 + l] = o;
}

// ---------------- K3: similarity GEMM + sigmoid-pool epilogue ----------------
// grid: 4096 = 256 frames x 4 pixel-tiles(64) x 4 k-tiles(64). 256 thr = 4 waves (2x2).
__global__ __launch_bounds__(256) void simk(const unsigned short* __restrict__ fbf,
                                            const unsigned short* __restrict__ abf,
                                            float* __restrict__ num, float* __restrict__ den,
                                            float* __restrict__ negnum, float* __restrict__ negden) {
  __shared__ unsigned short Alds[2][64][32];
  __shared__ unsigned short Blds[2][64][32];
  const int tid = threadIdx.x;
  const int l = tid & 63, w = tid >> 6;
  const int wm = w >> 1, wn = w & 1;
  const int bid = blockIdx.x;
  const int kt = bid & 3;
  const int pt = (bid >> 2) & 3;
  const int n  = bid >> 4;

  // staging: wave w loads rows [16w,16w+16); lane l -> row 16w+(l>>2), col (l&3)*8
  const int srow = w * 16 + (l >> 2);
  const int scol = (l & 3) * 8;
  const int p = pt * 64 + srow;
  const int pc = (p < HW) ? p : 0;   // clamp pad rows (masked in epilogue)
  const unsigned short* ag = fbf + ((size_t)n * HW + pc) * CH + scol;
  const unsigned short* bg = abf + (size_t)(kt * 64 + srow) * CH + scol;

  // prologue stage (t=0 -> buf 0)
  GLL(ag, &Alds[0][w * 16][0]);
  GLL(bg, &Blds[0][w * 16][0]);
  __syncthreads();   // drains vmcnt

  f32x4 acc[2][2] = {};
  const int rA0 = wm * 32 + (l & 15);
  const int rB0 = wn * 32 + (l & 15);
  const int kg8 = (l >> 4) * 8;
  int buf = 0;

  for (int t = 0; t < 16; ++t) {
    if (t < 15) {
      GLL(ag + (t + 1) * 32, &Alds[buf ^ 1][w * 16][0]);
      GLL(bg + (t + 1) * 32, &Blds[buf ^ 1][w * 16][0]);
    }
    bf16x8 a0 = *reinterpret_cast<const bf16x8*>(&Alds[buf][rA0][kg8]);
    bf16x8 a1 = *reinterpret_cast<const bf16x8*>(&Alds[buf][rA0 + 16][kg8]);
    bf16x8 b0 = *reinterpret_cast<const bf16x8*>(&Blds[buf][rB0][kg8]);
    bf16x8 b1 = *reinterpret_cast<const bf16x8*>(&Blds[buf][rB0 + 16][kg8]);
    acc[0][0] = __builtin_amdgcn_mfma_f32_16x16x32_bf16(a0, b0, acc[0][0], 0, 0, 0);
    acc[0][1] = __builtin_amdgcn_mfma_f32_16x16x32_bf16(a0, b1, acc[0][1], 0, 0, 0);
    acc[1][0] = __builtin_amdgcn_mfma_f32_16x16x32_bf16(a1, b0, acc[1][0], 0, 0, 0);
    acc[1][1] = __builtin_amdgcn_mfma_f32_16x16x32_bf16(a1, b1, acc[1][1], 0, 0, 0);
    __syncthreads();   // drains vmcnt(0)+lgkmcnt(0) per compiler semantics
    buf ^= 1;
  }

  // epilogue: C layout col=lane&15, row=(lane>>4)*4+j  [m89-verified]
  const int colL = l & 15;
  const int rg = l >> 4;
  float cnum[2] = {0.f, 0.f}, cden[2] = {0.f, 0.f};
  float ngn = 0.f, ngd = 0.f;
  bool hasneg = false;
#pragma unroll
  for (int mf = 0; mf < 2; ++mf) {
#pragma unroll
    for (int nf = 0; nf < 2; ++nf) {
      const int kglob = kt * 64 + wn * 32 + nf * 16 + colL;
#pragma unroll
      for (int j = 0; j < 4; ++j) {
        float s = acc[mf][nf][j];
        int row = wm * 32 + mf * 16 + rg * 4 + j;
        bool valid = (pt * 64 + row) < HW;
        float wp = valid ? sigmoidf_((s - EPS_POS) * INV_TAU) : 0.f;
        cnum[nf] += wp * s;
        cden[nf] += wp;
        if (valid && kglob == n) {
          float wneg = 1.f - sigmoidf_((s - EPS_NEG) * INV_TAU);
          ngn += wneg * s;
          ngd += wneg;
          hasneg = true;
        }
      }
    }
  }
  if (hasneg) { atomicAdd(&negnum[n], ngn); atomicAdd(&negden[n], ngd); }
#pragma unroll
  for (int nf = 0; nf < 2; ++nf) {
    float v = cnum[nf], d2 = cden[nf];
    v  += __shfl_xor(v, 16);  v  += __shfl_xor(v, 32);
    d2 += __shfl_xor(d2, 16); d2 += __shfl_xor(d2, 32);
    if (rg == 0) {
      int kglob = kt * 64 + wn * 32 + nf * 16 + colL;
      atomicAdd(&num[n * NFR + kglob], v);
      atomicAdd(&den[n * NFR + kglob], d2);
    }
  }
}

// ---------------- K4: finalize loss (NOTE the (N,1)/(N,) -> (N,N) broadcast!) ---
__global__ __launch_bounds__(256) void finalize_k(const float* __restrict__ num,
                                                  const float* __restrict__ den,
                                                  const float* __restrict__ negnum,
                                                  const float* __restrict__ negden,
                                                  float* __restrict__ out) {
  __shared__ float Pi_d[NFR], Ni_d[NFR], red[4];
  const int tid = threadIdx.x;
  const int l = tid & 63, w = tid >> 6;
  // phase A: wave w computes rows r = w, w+4, ... (coalesced per-wave reads)
  for (int r = w; r < NFR; r += 4) {
    float vsum = 0.f, pvac = 0.f;
#pragma unroll
    for (int cb = 0; cb < 4; ++cb) {
      int k = cb * 64 + l;
      float ratio = num[r * NFR + k] / den[r * NFR + k];
      vsum += ratio;
      if (k == r) pvac = ratio;
    }
#pragma unroll
    for (int m = 1; m < 64; m <<= 1) {
      vsum += __shfl_xor(vsum, m);
      pvac += __shfl_xor(pvac, m);
    }
    if (l == 0) {
      float Pi = pvac;
      float nh = negnum[r] / negden[r];
      Pi_d[r] = TEMP * Pi;
      // masked easy-sum = vsum - Pi + (-99*Pi) = vsum - 100*Pi
      Ni_d[r] = TEMP * (nh + vsum - 100.f * Pi);
    }
  }
  __syncthreads();
  // phase B: loss = (1/N) * sum_{i,j} softplus(Ni_d[j] - Pi_d[i])
  float pd = Pi_d[tid];
  float s = 0.f;
  for (int j = 0; j < NFR; ++j) {
    float x = Ni_d[j] - pd;
    s += (x > 0.f) ? (x + log1pf(__expf(-x))) : log1pf(__expf(x));
  }
#pragma unroll
  for (int m = 1; m < 64; m <<= 1) s += __shfl_xor(s, m);
  if (l == 0) red[w] = s;
  __syncthreads();
  if (tid == 0) out[0] = (red[0] + red[1] + red[2] + red[3]) * (1.0f / (float)NFR);
}

extern "C" void kernel_launch(void* const* d_in, const int* in_sizes, int n_in,
                              void* d_out, int out_size, void* d_ws, size_t ws_size,
                              hipStream_t stream) {
  const float* frame = (const float*)d_in[0];   // (256,14,14,512) f32
  const float* audio = (const float*)d_in[1];   // (256,512) f32
  float* out = (float*)d_out;                   // scalar f32

  char* ws = (char*)d_ws;
  unsigned short* abf = (unsigned short*)ws;                       // 256*512*2   = 256 KB
  unsigned short* fbf = (unsigned short*)(ws + 262144);            // 50176*512*2 = 51.4 MB
  float* num    = (float*)(ws + 262144 + 51380224);                // 256*256 f32
  float* den    = num + NFR * NFR;
  float* negnum = den + NFR * NFR;
  float* negden = negnum + NFR;

  // zero accumulators (ws is poisoned 0xAA before every launch)
  hipMemsetAsync(num, 0, (size_t)(2 * NFR * NFR + 2 * NFR) * sizeof(float), stream);

  audio_norm_k<<<256, 64, 0, stream>>>(audio, abf);
  frame_norm_k<<<12544, 256, 0, stream>>>(frame, fbf);
  simk<<<4096, 256, 0, stream>>>(fbf, abf, num, den, negnum, negden);
  finalize_k<<<1, 256, 0, stream>>>(num, den, negnum, negden, out);
}

// Round 2
// 216.870 us; speedup vs baseline: 1.5410x; 1.5410x over previous
//
#include <hip/hip_runtime.h>
#include <stdint.h>

#define NFR 256
#define HW 196
#define CH 512
#define EPS_POS 0.65f
#define EPS_NEG 0.40f
#define INV_TAU (1.0f/0.03f)
#define TEMP 0.07f

typedef __bf16 bf16x8 __attribute__((ext_vector_type(8)));
typedef float f32x4 __attribute__((ext_vector_type(4)));

typedef const __attribute__((address_space(1))) unsigned int* as1_u32p;
typedef __attribute__((address_space(3))) unsigned int* as3_u32p;
#define GLL(gp, lp) __builtin_amdgcn_global_load_lds((as1_u32p)(const void*)(gp), (as3_u32p)(void*)(lp), 16, 0, 0)

__device__ __forceinline__ float sigmoidf_(float x) {
  return 1.0f / (1.0f + __expf(-x));
}

// round-to-nearest-even f32 -> bf16 bits (inputs are finite)
__device__ __forceinline__ unsigned short f2bf(float x) {
  unsigned int u = __float_as_uint(x);
  unsigned int r = u + 0x7FFFu + ((u >> 16) & 1u);
  return (unsigned short)(r >> 16);
}

// ---------------- K1: audio L2-normalize -> bf16 [256][512] ----------------
__global__ __launch_bounds__(64) void audio_norm_k(const float* __restrict__ audio,
                                                   unsigned short* __restrict__ abf) {
  const int r = blockIdx.x;
  const int l = threadIdx.x;
  const float4* src = reinterpret_cast<const float4*>(audio + (size_t)r * CH);
  float4 a = src[l];
  float4 b = src[64 + l];
  float ss = a.x*a.x + a.y*a.y + a.z*a.z + a.w*a.w
           + b.x*b.x + b.y*b.y + b.z*b.z + b.w*b.w;
#pragma unroll
  for (int m = 1; m < 64; m <<= 1) ss += __shfl_xor(ss, m);
  float sc = rsqrtf(ss);
  ushort4 o;
  o.x = f2bf(a.x*sc); o.y = f2bf(a.y*sc); o.z = f2bf(a.z*sc); o.w = f2bf(a.w*sc);
  reinterpret_cast<ushort4*>(abf + (size_t)r * CH)[l] = o;
  o.x = f2bf(b.x*sc); o.y = f2bf(b.y*sc); o.z = f2bf(b.z*sc); o.w = f2bf(b.w*sc);
  reinterpret_cast<ushort4*>(abf + (size_t)r * CH)[64 + l] = o;
}

// ---------------- K2: frame L2-normalize -> bf16 [50176][512] ----------------
__global__ __launch_bounds__(256) void frame_norm_k(const float* __restrict__ frame,
                                                    unsigned short* __restrict__ fbf) {
  const int w = threadIdx.x >> 6;
  const int l = threadIdx.x & 63;
  const size_t r = (size_t)blockIdx.x * 4 + w;   // < 50176 exact
  const float4* src = reinterpret_cast<const float4*>(frame + r * CH);
  float4 a = src[l];
  float4 b = src[64 + l];
  float ss = a.x*a.x + a.y*a.y + a.z*a.z + a.w*a.w
           + b.x*b.x + b.y*b.y + b.z*b.z + b.w*b.w;
#pragma unroll
  for (int m = 1; m < 64; m <<= 1) ss += __shfl_xor(ss, m);
  float sc = rsqrtf(ss);
  ushort4 o;
  o.x = f2bf(a.x*sc); o.y = f2bf(a.y*sc); o.z = f2bf(a.z*sc); o.w = f2bf(a.w*sc);
  reinterpret_cast<ushort4*>(fbf + r * CH)[l] = o;
  o.x = f2bf(b.x*sc); o.y = f2bf(b.y*sc); o.z = f2bf(b.z*sc); o.w = f2bf(b.w*sc);
  reinterpret_cast<ushort4*>(fbf + r * CH)[64 + l] = o;
}

// ---------------- K3: flat GEMM (50176x256x512) + sigmoid-pool epilogue -------
// 784 blocks = 392 Mtiles x 2 Ntiles. 256 thr = 4 waves (2x2), 128x128 tile, BK=32.
__global__ __launch_bounds__(256, 2) void simk(const unsigned short* __restrict__ fbf,
                                               const unsigned short* __restrict__ abf,
                                               float* __restrict__ num, float* __restrict__ den,
                                               float* __restrict__ negnum, float* __restrict__ negden) {
  __shared__ unsigned short Alds[2][128][32];
  __shared__ unsigned short Blds[2][128][32];
  const int tid = threadIdx.x;
  const int l = tid & 63, w = tid >> 6;
  const int wm = w >> 1, wn = w & 1;

  // bijective XCD swizzle: 784 = 8*98; consecutive vids (mt pairs share A) same XCD
  const int bid = blockIdx.x;
  const int vid = (bid & 7) * 98 + (bid >> 3);
  const int mt = vid >> 1;           // 0..391
  const int nt = vid & 1;            // 0..1
  const int m0 = mt * 128;           // global pixel row base
  const int n0col = nt * 128;        // audio col base

  // staging: round q in {0,1}: LDS rows q*64 + w*16 .. +15; lane l -> row +(l>>2), ch (l&3)*8
  const int srow = w * 16 + (l >> 2);
  const int scol = (l & 3) * 8;
  const unsigned short* agA = fbf + (size_t)(m0 + srow) * CH + scol;
  const unsigned short* agB = abf + (size_t)(n0col + srow) * CH + scol;

  GLL(agA,          &Alds[0][w * 16][0]);
  GLL(agA + 64*CH,  &Alds[0][64 + w * 16][0]);
  GLL(agB,          &Blds[0][w * 16][0]);
  GLL(agB + 64*CH,  &Blds[0][64 + w * 16][0]);
  __syncthreads();

  f32x4 acc[4][4] = {};
  const int rA0 = wm * 64 + (l & 15);
  const int rB0 = wn * 64 + (l & 15);
  const int kg8 = (l >> 4) * 8;
  int buf = 0;

  for (int t = 0; t < 16; ++t) {
    if (t < 15) {
      const unsigned short* a2 = agA + (t + 1) * 32;
      const unsigned short* b2 = agB + (t + 1) * 32;
      GLL(a2,          &Alds[buf ^ 1][w * 16][0]);
      GLL(a2 + 64*CH,  &Alds[buf ^ 1][64 + w * 16][0]);
      GLL(b2,          &Blds[buf ^ 1][w * 16][0]);
      GLL(b2 + 64*CH,  &Blds[buf ^ 1][64 + w * 16][0]);
    }
    bf16x8 af[4], bfr[4];
#pragma unroll
    for (int i = 0; i < 4; ++i) {
      af[i]  = *reinterpret_cast<const bf16x8*>(&Alds[buf][rA0 + i * 16][kg8]);
      bfr[i] = *reinterpret_cast<const bf16x8*>(&Blds[buf][rB0 + i * 16][kg8]);
    }
#pragma unroll
    for (int i = 0; i < 4; ++i)
#pragma unroll
      for (int j2 = 0; j2 < 4; ++j2)
        acc[i][j2] = __builtin_amdgcn_mfma_f32_16x16x32_bf16(af[i], bfr[j2], acc[i][j2], 0, 0, 0);
    __syncthreads();
    buf ^= 1;
  }

  // ---- epilogue: C layout col=lane&15, row=(lane>>4)*4+j  [m89-verified] ----
  const int rg = l >> 4;
  const int colL = l & 15;
  const int wrow0 = m0 + wm * 64;      // wave's first global pixel row
  const int nlo = wrow0 / HW;          // wave spans at most 2 frames (64 < 196)
  const int nhi = (wrow0 + 63) / HW;

  float cn0[4] = {}, cd0[4] = {}, cn1[4] = {}, cd1[4] = {};
  float ngn = 0.f, ngd = 0.f;
  bool hasneg = false;
#pragma unroll
  for (int i = 0; i < 4; ++i) {
#pragma unroll
    for (int jj = 0; jj < 4; ++jj) {
      const int P = wrow0 + i * 16 + rg * 4 + jj;
      const int nrow = P / HW;                     // magic-mul
      const bool lo = (nrow == nlo);
#pragma unroll
      for (int j2 = 0; j2 < 4; ++j2) {
        const float s = acc[i][j2][jj];
        const float wp = sigmoidf_((s - EPS_POS) * INV_TAU);
        const float wps = wp * s;
        if (lo) { cn0[j2] += wps; cd0[j2] += wp; }
        else    { cn1[j2] += wps; cd1[j2] += wp; }
        const int kglob = n0col + wn * 64 + j2 * 16 + colL;
        if (kglob == nrow) {
          const float wneg = 1.f - sigmoidf_((s - EPS_NEG) * INV_TAU);
          ngn += wneg * s; ngd += wneg; hasneg = true;
        }
      }
    }
  }
  if (hasneg) { atomicAdd(&negnum[nlo == nhi ? nlo : (colL + n0col + wn*64 >= 0 ? 0 : 0), 0] , 0.f); } // placeholder removed below
  // (diagonal: each lane's matches all belong to nrow == kglob; add per lane)
  if (hasneg) {
    // every matched element in this lane has the same k (= kglob varies by j2) —
    // but a lane can match at most one (j2,colL) pair per row; accumulate per-lane is safe
  }

#pragma unroll
  for (int j2 = 0; j2 < 4; ++j2) {
    float v0 = cn0[j2], d0 = cd0[j2], v1 = cn1[j2], d1 = cd1[j2];
    v0 += __shfl_xor(v0, 16); v0 += __shfl_xor(v0, 32);
    d0 += __shfl_xor(d0, 16); d0 += __shfl_xor(d0, 32);
    v1 += __shfl_xor(v1, 16); v1 += __shfl_xor(v1, 32);
    d1 += __shfl_xor(d1, 16); d1 += __shfl_xor(d1, 32);
    if (rg == 0) {
      const int kglob = n0col + wn * 64 + j2 * 16 + colL;
      atomicAdd(&num[nlo * NFR + kglob], v0);
      atomicAdd(&den[nlo * NFR + kglob], d0);
      if (nhi != nlo) {
        atomicAdd(&num[nhi * NFR + kglob], v1);
        atomicAdd(&den[nhi * NFR + kglob], d1);
      }
    }
  }
  if (hasneg) {
    // lane's matches: rows where n(row) == its kglob; nrow in {nlo,nhi}; k uniquely = nrow
    // (ngn/ngd may mix nlo and nhi matches only if BOTH kglob values matched — impossible
    //  since kglob differs by j2 but nrow values differ per row; a lane can match nlo at
    //  one j2 and nhi at another j2. Split guard: recompute per-group sums was avoided by
    //  noting matches with nrow==nlo all add to negnum[nlo], nrow==nhi to negnum[nhi].
    //  To stay exact, redo the tiny loop here (cheap, only matched lanes):
    float gn0 = 0.f, gd0 = 0.f, gn1 = 0.f, gd1 = 0.f;
#pragma unroll
    for (int i = 0; i < 4; ++i) {
#pragma unroll
      for (int jj = 0; jj < 4; ++jj) {
        const int P = wrow0 + i * 16 + rg * 4 + jj;
        const int nrow = P / HW;
#pragma unroll
        for (int j2 = 0; j2 < 4; ++j2) {
          const int kglob = n0col + wn * 64 + j2 * 16 + colL;
          if (kglob == nrow) {
            const float s = acc[i][j2][jj];
            const float wneg = 1.f - sigmoidf_((s - EPS_NEG) * INV_TAU);
            if (nrow == nlo) { gn0 += wneg * s; gd0 += wneg; }
            else             { gn1 += wneg * s; gd1 += wneg; }
          }
        }
      }
    }
    if (gd0 > 0.f) { atomicAdd(&negnum[nlo], gn0); atomicAdd(&negden[nlo], gd0); }
    if (gd1 > 0.f) { atomicAdd(&negnum[nhi], gn1); atomicAdd(&negden[nhi], gd1); }
  }
}

// ---------------- K4a: per-row stats ----------------
__global__ __launch_bounds__(64) void rowstats_k(const float* __restrict__ num,
                                                 const float* __restrict__ den,
                                                 const float* __restrict__ negnum,
                                                 const float* __restrict__ negden,
                                                 float* __restrict__ Pi_d,
                                                 float* __restrict__ Ni_d) {
  const int r = blockIdx.x;
  const int l = threadIdx.x;
  float vsum = 0.f, pvac = 0.f;
#pragma unroll
  for (int cb = 0; cb < 4; ++cb) {
    const int k = cb * 64 + l;
    const float ratio = num[r * NFR + k] / den[r * NFR + k];
    vsum += ratio;
    if (k == r) pvac = ratio;
  }
#pragma unroll
  for (int m = 1; m < 64; m <<= 1) {
    vsum += __shfl_xor(vsum, m);
    pvac += __shfl_xor(pvac, m);
  }
  if (l == 0) {
    const float nh = negnum[r] / negden[r];
    Pi_d[r] = TEMP * pvac;
    Ni_d[r] = TEMP * (nh + vsum - 100.f * pvac);   // masked easy-sum
  }
}

// ---------------- K4b: loss = (1/N) sum_{i,j} softplus(Ni_d[j]-Pi_d[i]) -------
__global__ __launch_bounds__(256) void loss_k(const float* __restrict__ Pi_d,
                                              const float* __restrict__ Ni_d,
                                              float* __restrict__ out) {
  __shared__ float red[4];
  const int i = blockIdx.x;
  const int tid = threadIdx.x;
  const int l = tid & 63, w = tid >> 6;
  const float x = Ni_d[tid] - Pi_d[i];
  const float m = fmaxf(x, 0.f);
  float sp = m + __logf(__expf(x - m) + __expf(-m));
#pragma unroll
  for (int s2 = 1; s2 < 64; s2 <<= 1) sp += __shfl_xor(sp, s2);
  if (l == 0) red[w] = sp;
  __syncthreads();
  if (tid == 0) atomicAdd(out, (red[0] + red[1] + red[2] + red[3]) * (1.0f / (float)NFR));
}

extern "C" void kernel_launch(void* const* d_in, const int* in_sizes, int n_in,
                              void* d_out, int out_size, void* d_ws, size_t ws_size,
                              hipStream_t stream) {
  const float* frame = (const float*)d_in[0];   // (256,14,14,512) f32
  const float* audio = (const float*)d_in[1];   // (256,512) f32
  float* out = (float*)d_out;                   // scalar f32

  char* ws = (char*)d_ws;
  unsigned short* abf = (unsigned short*)ws;                       // 256 KB
  unsigned short* fbf = (unsigned short*)(ws + 262144);            // 51.4 MB
  float* num    = (float*)(ws + 262144 + 51380224);
  float* den    = num + NFR * NFR;
  float* negnum = den + NFR * NFR;
  float* negden = negnum + NFR;
  float* Pi_d   = negden + NFR;
  float* Ni_d   = Pi_d + NFR;

  hipMemsetAsync(num, 0, (size_t)(2 * NFR * NFR + 2 * NFR) * sizeof(float), stream);
  hipMemsetAsync(out, 0, sizeof(float), stream);

  audio_norm_k<<<256, 64, 0, stream>>>(audio, abf);
  frame_norm_k<<<12544, 256, 0, stream>>>(frame, fbf);
  simk<<<784, 256, 0, stream>>>(fbf, abf, num, den, negnum, negden);
  rowstats_k<<<256, 64, 0, stream>>>(num, den, negnum, negden, Pi_d, Ni_d);
  loss_k<<<256, 256, 0, stream>>>(Pi_d, Ni_d, out);
}

// Round 3
// 202.565 us; speedup vs baseline: 1.6498x; 1.0706x over previous
//
#include <hip/hip_runtime.h>
#include <stdint.h>

#define NFR 256
#define HW 196
#define CH 512
#define EPS_POS 0.65f
#define EPS_NEG 0.40f
#define INV_TAU (1.0f/0.03f)
#define TEMP 0.07f

typedef __bf16 bf16x8 __attribute__((ext_vector_type(8)));
typedef float f32x4 __attribute__((ext_vector_type(4)));

typedef const __attribute__((address_space(1))) unsigned int* as1_u32p;
typedef __attribute__((address_space(3))) unsigned int* as3_u32p;
#define GLL(gp, lp) __builtin_amdgcn_global_load_lds((as1_u32p)(const void*)(gp), (as3_u32p)(void*)(lp), 16, 0, 0)

__device__ __forceinline__ float sigmoidf_(float x) {
  return 1.0f / (1.0f + __expf(-x));
}

// round-to-nearest-even f32 -> bf16 bits (inputs finite)
__device__ __forceinline__ unsigned short f2bf(float x) {
  unsigned int u = __float_as_uint(x);
  unsigned int r = u + 0x7FFFu + ((u >> 16) & 1u);
  return (unsigned short)(r >> 16);
}

// ---------------- K1: audio L2-normalize -> bf16 [256][512] ----------------
__global__ __launch_bounds__(64) void audio_norm_k(const float* __restrict__ audio,
                                                   unsigned short* __restrict__ abf) {
  const int r = blockIdx.x;
  const int l = threadIdx.x;
  const float4* src = reinterpret_cast<const float4*>(audio + (size_t)r * CH);
  float4 a = src[l];
  float4 b = src[64 + l];
  float ss = a.x*a.x + a.y*a.y + a.z*a.z + a.w*a.w
           + b.x*b.x + b.y*b.y + b.z*b.z + b.w*b.w;
#pragma unroll
  for (int m = 1; m < 64; m <<= 1) ss += __shfl_xor(ss, m);
  float sc = rsqrtf(ss);
  ushort4 o;
  o.x = f2bf(a.x*sc); o.y = f2bf(a.y*sc); o.z = f2bf(a.z*sc); o.w = f2bf(a.w*sc);
  reinterpret_cast<ushort4*>(abf + (size_t)r * CH)[l] = o;
  o.x = f2bf(b.x*sc); o.y = f2bf(b.y*sc); o.z = f2bf(b.z*sc); o.w = f2bf(b.w*sc);
  reinterpret_cast<ushort4*>(abf + (size_t)r * CH)[64 + l] = o;
}

// ---------------- K2: frame L2-normalize -> bf16 [50176][512] ----------------
__global__ __launch_bounds__(256) void frame_norm_k(const float* __restrict__ frame,
                                                    unsigned short* __restrict__ fbf) {
  const int w = threadIdx.x >> 6;
  const int l = threadIdx.x & 63;
  const size_t r = (size_t)blockIdx.x * 4 + w;   // < 50176 exact
  const float4* src = reinterpret_cast<const float4*>(frame + r * CH);
  float4 a = src[l];
  float4 b = src[64 + l];
  float ss = a.x*a.x + a.y*a.y + a.z*a.z + a.w*a.w
           + b.x*b.x + b.y*b.y + b.z*b.z + b.w*b.w;
#pragma unroll
  for (int m = 1; m < 64; m <<= 1) ss += __shfl_xor(ss, m);
  float sc = rsqrtf(ss);
  ushort4 o;
  o.x = f2bf(a.x*sc); o.y = f2bf(a.y*sc); o.z = f2bf(a.z*sc); o.w = f2bf(a.w*sc);
  reinterpret_cast<ushort4*>(fbf + r * CH)[l] = o;
  o.x = f2bf(b.x*sc); o.y = f2bf(b.y*sc); o.z = f2bf(b.z*sc); o.w = f2bf(b.w*sc);
  reinterpret_cast<ushort4*>(fbf + r * CH)[64 + l] = o;
}

// ---------------- K3: flat GEMM (50176 x 256 x 512), 64x256 tile -------------
// 784 blocks (3.06/CU). 256 thr = 4 waves; wave w owns cols [64w, 64w+64).
// A read exactly once. LDS XOR-swizzle (cblk ^= (row>>1)&3) applied on BOTH the
// per-lane global staging source and the ds_read col (LDS dest stays linear for
// global_load_lds) -> conflict-free b128 reads.
__global__ __launch_bounds__(256, 3) void simk(const unsigned short* __restrict__ fbf,
                                               const unsigned short* __restrict__ abf,
                                               float* __restrict__ num, float* __restrict__ den,
                                               float* __restrict__ negnum, float* __restrict__ negden) {
  __shared__ unsigned short Alds[2][64][32];    // 8 KB  x2
  __shared__ unsigned short Blds[2][256][32];   // 32 KB x2
  const int tid = threadIdx.x;
  const int l = tid & 63, w = tid >> 6;
  const int m0 = blockIdx.x * 64;

  // ---- staging: lane l -> LDS (row = base + (l>>2), cblk_lds = l&3); content is
  // global cblk_g = (l&3) ^ ((row>>1)&3) = (l&3) ^ ((l>>3)&3)  [base rows %16==0]
  const int scol = (((l & 3) ^ ((l >> 3) & 3)) * 8);   // channels
  const unsigned short* agA = fbf + (size_t)(m0 + 16 * w + (l >> 2)) * CH + scol;
  const unsigned short* agB = abf + (size_t)(64 * w + (l >> 2)) * CH + scol;

  // prologue: stage K-step 0 into buf 0 (wave w: 1 A-GLL + 4 B-GLLs)
  GLL(agA, &Alds[0][16 * w][0]);
#pragma unroll
  for (int q = 0; q < 4; ++q)
    GLL(agB + (size_t)(16 * q) * CH, &Blds[0][64 * w + 16 * q][0]);
  __syncthreads();

  f32x4 acc[4][4] = {};
  const int rA = l & 15;
  // swizzled read col byte offset: (kg ^ ((row>>1)&3))<<4 ; row%... -> lane-const
  const int cswz = (((l >> 4) ^ ((l >> 1) & 3)) << 4);
  int buf = 0;

  for (int t = 0; t < 16; ++t) {
    if (t < 15) {
      const int ko = (t + 1) * 32;
      GLL(agA + ko, &Alds[buf ^ 1][16 * w][0]);
#pragma unroll
      for (int q = 0; q < 4; ++q)
        GLL(agB + ko + (size_t)(16 * q) * CH, &Blds[buf ^ 1][64 * w + 16 * q][0]);
    }
    const char* Ab = (const char*)&Alds[buf][0][0] + rA * 64 + cswz;
    const char* Bb = (const char*)&Blds[buf][0][0] + (64 * w + rA) * 64 + cswz;
    bf16x8 af[4], bfr[4];
#pragma unroll
    for (int i = 0; i < 4; ++i) {
      af[i]  = *reinterpret_cast<const bf16x8*>(Ab + 1024 * i);
      bfr[i] = *reinterpret_cast<const bf16x8*>(Bb + 1024 * i);
    }
#pragma unroll
    for (int i = 0; i < 4; ++i)
#pragma unroll
      for (int j = 0; j < 4; ++j)
        acc[i][j] = __builtin_amdgcn_mfma_f32_16x16x32_bf16(af[i], bfr[j], acc[i][j], 0, 0, 0);
    __syncthreads();
    buf ^= 1;
  }

  // ---- epilogue: C layout col=lane&15, row=(lane>>4)*4+jj  [m89-verified] ----
  const int rg = l >> 4;
  const int colL = l & 15;
  const int nlo = m0 / HW;            // block's 64 rows span <=2 frames
  const int nhi = (m0 + 63) / HW;

  float cn0[4] = {}, cd0[4] = {}, cn1[4] = {}, cd1[4] = {};
  float gn0 = 0.f, gd0 = 0.f, gn1 = 0.f, gd1 = 0.f;
#pragma unroll
  for (int i = 0; i < 4; ++i) {
#pragma unroll
    for (int jj = 0; jj < 4; ++jj) {
      const int P = m0 + i * 16 + rg * 4 + jj;
      const int nrow = P / HW;        // magic-mul
      const bool lo = (nrow == nlo);
#pragma unroll
      for (int j = 0; j < 4; ++j) {
        const float s = acc[i][j][jj];
        const float wp = sigmoidf_((s - EPS_POS) * INV_TAU);
        const float wps = wp * s;
        if (lo) { cn0[j] += wps; cd0[j] += wp; }
        else    { cn1[j] += wps; cd1[j] += wp; }
        const int kglob = w * 64 + j * 16 + colL;
        if (kglob == nrow) {
          const float wneg = 1.f - sigmoidf_((s - EPS_NEG) * INV_TAU);
          if (lo) { gn0 += wneg * s; gd0 += wneg; }
          else    { gn1 += wneg * s; gd1 += wneg; }
        }
      }
    }
  }
  if (gd0 > 0.f) { atomicAdd(&negnum[nlo], gn0); atomicAdd(&negden[nlo], gd0); }
  if (gd1 > 0.f) { atomicAdd(&negnum[nhi], gn1); atomicAdd(&negden[nhi], gd1); }

#pragma unroll
  for (int j = 0; j < 4; ++j) {
    float v0 = cn0[j], d0 = cd0[j], v1 = cn1[j], d1 = cd1[j];
    v0 += __shfl_xor(v0, 16); v0 += __shfl_xor(v0, 32);
    d0 += __shfl_xor(d0, 16); d0 += __shfl_xor(d0, 32);
    v1 += __shfl_xor(v1, 16); v1 += __shfl_xor(v1, 32);
    d1 += __shfl_xor(d1, 16); d1 += __shfl_xor(d1, 32);
    if (rg == 0) {
      const int kglob = w * 64 + j * 16 + colL;
      atomicAdd(&num[nlo * NFR + kglob], v0);
      atomicAdd(&den[nlo * NFR + kglob], d0);
      if (nhi != nlo) {
        atomicAdd(&num[nhi * NFR + kglob], v1);
        atomicAdd(&den[nhi * NFR + kglob], d1);
      }
    }
  }
}

// ---------------- K4a: per-row stats ----------------
__global__ __launch_bounds__(64) void rowstats_k(const float* __restrict__ num,
                                                 const float* __restrict__ den,
                                                 const float* __restrict__ negnum,
                                                 const float* __restrict__ negden,
                                                 float* __restrict__ Pi_d,
                                                 float* __restrict__ Ni_d) {
  const int r = blockIdx.x;
  const int l = threadIdx.x;
  float vsum = 0.f, pvac = 0.f;
#pragma unroll
  for (int cb = 0; cb < 4; ++cb) {
    const int k = cb * 64 + l;
    const float ratio = num[r * NFR + k] / den[r * NFR + k];
    vsum += ratio;
    if (k == r) pvac = ratio;
  }
#pragma unroll
  for (int m = 1; m < 64; m <<= 1) {
    vsum += __shfl_xor(vsum, m);
    pvac += __shfl_xor(pvac, m);
  }
  if (l == 0) {
    const float nh = negnum[r] / negden[r];
    Pi_d[r] = TEMP * pvac;
    Ni_d[r] = TEMP * (nh + vsum - 100.f * pvac);   // masked easy-sum
  }
}

// ---------------- K4b: loss = (1/N) sum_{i,j} softplus(Ni_d[j]-Pi_d[i]) -------
__global__ __launch_bounds__(256) void loss_k(const float* __restrict__ Pi_d,
                                              const float* __restrict__ Ni_d,
                                              float* __restrict__ out) {
  __shared__ float red[4];
  const int i = blockIdx.x;
  const int tid = threadIdx.x;
  const int l = tid & 63, w = tid >> 6;
  const float x = Ni_d[tid] - Pi_d[i];
  const float m = fmaxf(x, 0.f);
  float sp = m + __logf(__expf(x - m) + __expf(-m));
#pragma unroll
  for (int s2 = 1; s2 < 64; s2 <<= 1) sp += __shfl_xor(sp, s2);
  if (l == 0) red[w] = sp;
  __syncthreads();
  if (tid == 0) atomicAdd(out, (red[0] + red[1] + red[2] + red[3]) * (1.0f / (float)NFR));
}

extern "C" void kernel_launch(void* const* d_in, const int* in_sizes, int n_in,
                              void* d_out, int out_size, void* d_ws, size_t ws_size,
                              hipStream_t stream) {
  const float* frame = (const float*)d_in[0];   // (256,14,14,512) f32
  const float* audio = (const float*)d_in[1];   // (256,512) f32
  float* out = (float*)d_out;                   // scalar f32

  char* ws = (char*)d_ws;
  unsigned short* abf = (unsigned short*)ws;                       // 256 KB
  unsigned short* fbf = (unsigned short*)(ws + 262144);            // 51.4 MB
  float* num    = (float*)(ws + 262144 + 51380224);
  float* den    = num + NFR * NFR;
  float* negnum = den + NFR * NFR;
  float* negden = negnum + NFR;
  float* Pi_d   = negden + NFR;
  float* Ni_d   = Pi_d + NFR;

  hipMemsetAsync(num, 0, (size_t)(2 * NFR * NFR + 2 * NFR) * sizeof(float), stream);
  hipMemsetAsync(out, 0, sizeof(float), stream);

  audio_norm_k<<<256, 64, 0, stream>>>(audio, abf);
  frame_norm_k<<<12544, 256, 0, stream>>>(frame, fbf);
  simk<<<784, 256, 0, stream>>>(fbf, abf, num, den, negnum, negden);
  rowstats_k<<<256, 64, 0, stream>>>(num, den, negnum, negden, Pi_d, Ni_d);
  loss_k<<<256, 256, 0, stream>>>(Pi_d, Ni_d, out);
}

// Round 4
// 189.131 us; speedup vs baseline: 1.7670x; 1.0710x over previous
//
#include <hip/hip_runtime.h>
#include <stdint.h>

#define NFR 256
#define HW 196
#define CH 512
#define EPS_POS 0.65f
#define EPS_NEG 0.40f
#define INV_TAU (1.0f/0.03f)
#define TEMP 0.07f

typedef __bf16 bf16x8 __attribute__((ext_vector_type(8)));
typedef float f32x4 __attribute__((ext_vector_type(4)));
typedef unsigned short u16x8 __attribute__((ext_vector_type(8)));

typedef const __attribute__((address_space(1))) unsigned int* as1_u32p;
typedef __attribute__((address_space(3))) unsigned int* as3_u32p;
#define GLL(gp, lp) __builtin_amdgcn_global_load_lds((as1_u32p)(const void*)(gp), (as3_u32p)(void*)(lp), 16, 0, 0)

__device__ __forceinline__ float sigmoidf_(float x) {
  return 1.0f / (1.0f + __expf(-x));
}

// round-to-nearest-even f32 -> bf16 bits (inputs finite)
__device__ __forceinline__ unsigned short f2bf(float x) {
  unsigned int u = __float_as_uint(x);
  unsigned int r = u + 0x7FFFu + ((u >> 16) & 1u);
  return (unsigned short)(r >> 16);
}

// ---------------- K1: audio L2-normalize -> bf16 [256][512]; also zero accums --
__global__ __launch_bounds__(64) void audio_norm_k(const float* __restrict__ audio,
                                                   unsigned short* __restrict__ abf,
                                                   float* __restrict__ numbase,   // num..den contiguous
                                                   float* __restrict__ negbase) { // negnum..negden contiguous
  const int r = blockIdx.x;
  const int l = threadIdx.x;
  // zero num+den: 131072 floats = 32768 float4; 16384 threads x 2
  {
    const int idx = r * 64 + l;
    f32x4 z = {0.f, 0.f, 0.f, 0.f};
    f32x4* p = (f32x4*)numbase;
    p[idx * 2] = z;
    p[idx * 2 + 1] = z;
    if (r < 2) ((f32x4*)negbase)[r * 64 + l] = z;   // 512 floats
  }
  const float4* src = reinterpret_cast<const float4*>(audio + (size_t)r * CH);
  float4 a = src[l];
  float4 b = src[64 + l];
  float ss = a.x*a.x + a.y*a.y + a.z*a.z + a.w*a.w
           + b.x*b.x + b.y*b.y + b.z*b.z + b.w*b.w;
#pragma unroll
  for (int m = 1; m < 64; m <<= 1) ss += __shfl_xor(ss, m);
  float sc = rsqrtf(ss);
  ushort4 o;
  o.x = f2bf(a.x*sc); o.y = f2bf(a.y*sc); o.z = f2bf(a.z*sc); o.w = f2bf(a.w*sc);
  reinterpret_cast<ushort4*>(abf + (size_t)r * CH)[l] = o;
  o.x = f2bf(b.x*sc); o.y = f2bf(b.y*sc); o.z = f2bf(b.z*sc); o.w = f2bf(b.w*sc);
  reinterpret_cast<ushort4*>(abf + (size_t)r * CH)[64 + l] = o;
}

// ---------------- K2: FUSED frame-normalize + GEMM (50176 x 256 x 512) --------
// 784 blocks x 64 rows. 4 waves; wave w owns output cols [64w, 64w+64).
// Phase 1: read raw f32 rows once, row-normalize, bf16 -> LDS Afull[64][512]
//   (XOR-swizzled 16B granules: g_phys = g ^ (row&7); written ds_write_b128).
// Phase 2: K-loop over 16 steps; B tile [256][32] staged via global_load_lds
//   (single buffer; pre-swizzled global source, swizzled read col — r3-verified).
__global__ __launch_bounds__(256, 2) void simk(const float* __restrict__ frame,
                                               const unsigned short* __restrict__ abf,
                                               float* __restrict__ num, float* __restrict__ den,
                                               float* __restrict__ negnum, float* __restrict__ negden) {
  __shared__ unsigned short Afull[64][512];   // 64 KB
  __shared__ unsigned short Blds[256][32];    // 16 KB  (80 KB total -> 2 blocks/CU)
  const int tid = threadIdx.x;
  const int l = tid & 63, w = tid >> 6;
  const int m0 = blockIdx.x * 64;

  // ---- B staging ptr (same scheme as r3): lane l -> LDS row base+(l>>2), cblk l&3;
  // content cblk_g = (l&3) ^ ((l>>3)&3)
  const int scolB = (((l & 3) ^ ((l >> 3) & 3)) * 8);
  const unsigned short* agB = abf + (size_t)(64 * w + (l >> 2)) * CH + scolB;

  // prologue: stage B(t=0) early so it flies under the norm phase
#pragma unroll
  for (int q = 0; q < 4; ++q)
    GLL(agB + (size_t)(16 * q) * CH, &Blds[64 * w + 16 * q][0]);

  // ---- Phase 1: normalize rows 16w..16w+15 into Afull ----
  {
    const int l8 = l * 8;
#pragma unroll 2
    for (int rr = 0; rr < 16; ++rr) {
      const int r = 16 * w + rr;
      const float4* src = reinterpret_cast<const float4*>(frame + (size_t)(m0 + r) * CH + l8);
      float4 a = src[0];
      float4 b = src[1];
      float ss = a.x*a.x + a.y*a.y + a.z*a.z + a.w*a.w
               + b.x*b.x + b.y*b.y + b.z*b.z + b.w*b.w;
#pragma unroll
      for (int m = 1; m < 64; m <<= 1) ss += __shfl_xor(ss, m);
      const float sc = rsqrtf(ss);
      u16x8 o;
      o[0] = f2bf(a.x*sc); o[1] = f2bf(a.y*sc); o[2] = f2bf(a.z*sc); o[3] = f2bf(a.w*sc);
      o[4] = f2bf(b.x*sc); o[5] = f2bf(b.y*sc); o[6] = f2bf(b.z*sc); o[7] = f2bf(b.w*sc);
      char* dst = (char*)&Afull[0][0] + r * 1024 + ((l ^ (r & 7)) << 4);
      *reinterpret_cast<u16x8*>(dst) = o;
    }
  }
  __syncthreads();   // norm writes + B(0) visible (barrier drains vm+lgkm)

  f32x4 acc[4][4] = {};
  const int rA = l & 15;
  const int aRowByte = rA * 1024;
  const int cswzB = (((l >> 4) ^ ((l >> 1) & 3)) << 4);

  for (int t = 0; t < 16; ++t) {
    // A granule: logical g = 4t + (l>>4), physical g ^ (row&7), row&7 = l&7
    const int gA = (((4 * t + (l >> 4)) ^ (l & 7)) << 4);
    const char* Ab = (const char*)&Afull[0][0] + aRowByte + gA;
    const char* Bb = (const char*)&Blds[0][0] + (64 * w + rA) * 64 + cswzB;
    bf16x8 af[4], bfr[4];
#pragma unroll
    for (int i = 0; i < 4; ++i) {
      af[i]  = *reinterpret_cast<const bf16x8*>(Ab + 16384 * i);   // +16 rows
      bfr[i] = *reinterpret_cast<const bf16x8*>(Bb + 1024 * i);    // +16 rows
    }
#pragma unroll
    for (int i = 0; i < 4; ++i)
#pragma unroll
      for (int j = 0; j < 4; ++j)
        acc[i][j] = __builtin_amdgcn_mfma_f32_16x16x32_bf16(af[i], bfr[j], acc[i][j], 0, 0, 0);
    __syncthreads();                       // all B reads retired
    if (t < 15) {
      const unsigned short* bsrc = agB + (t + 1) * 32;
#pragma unroll
      for (int q = 0; q < 4; ++q)
        GLL(bsrc + (size_t)(16 * q) * CH, &Blds[64 * w + 16 * q][0]);
      __syncthreads();                     // B(t+1) visible
    }
  }

  // ---- epilogue: C layout col=lane&15, row=(lane>>4)*4+jj  [m89-verified] ----
  const int rg = l >> 4;
  const int colL = l & 15;
  const int nlo = m0 / HW;
  const int nhi = (m0 + 63) / HW;

  float cn0[4] = {}, cd0[4] = {}, cn1[4] = {}, cd1[4] = {};
  float gn0 = 0.f, gd0 = 0.f, gn1 = 0.f, gd1 = 0.f;
#pragma unroll
  for (int i = 0; i < 4; ++i) {
#pragma unroll
    for (int jj = 0; jj < 4; ++jj) {
      const int P = m0 + i * 16 + rg * 4 + jj;
      const int nrow = P / HW;
      const bool lo = (nrow == nlo);
#pragma unroll
      for (int j = 0; j < 4; ++j) {
        const float s = acc[i][j][jj];
        const float wp = sigmoidf_((s - EPS_POS) * INV_TAU);
        const float wps = wp * s;
        if (lo) { cn0[j] += wps; cd0[j] += wp; }
        else    { cn1[j] += wps; cd1[j] += wp; }
        const int kglob = w * 64 + j * 16 + colL;
        if (kglob == nrow) {
          const float wneg = 1.f - sigmoidf_((s - EPS_NEG) * INV_TAU);
          if (lo) { gn0 += wneg * s; gd0 += wneg; }
          else    { gn1 += wneg * s; gd1 += wneg; }
        }
      }
    }
  }
  if (gd0 > 0.f) { atomicAdd(&negnum[nlo], gn0); atomicAdd(&negden[nlo], gd0); }
  if (gd1 > 0.f) { atomicAdd(&negnum[nhi], gn1); atomicAdd(&negden[nhi], gd1); }

#pragma unroll
  for (int j = 0; j < 4; ++j) {
    float v0 = cn0[j], d0 = cd0[j], v1 = cn1[j], d1 = cd1[j];
    v0 += __shfl_xor(v0, 16); v0 += __shfl_xor(v0, 32);
    d0 += __shfl_xor(d0, 16); d0 += __shfl_xor(d0, 32);
    v1 += __shfl_xor(v1, 16); v1 += __shfl_xor(v1, 32);
    d1 += __shfl_xor(d1, 16); d1 += __shfl_xor(d1, 32);
    if (rg == 0) {
      const int kglob = w * 64 + j * 16 + colL;
      atomicAdd(&num[nlo * NFR + kglob], v0);
      atomicAdd(&den[nlo * NFR + kglob], d0);
      if (nhi != nlo) {
        atomicAdd(&num[nhi * NFR + kglob], v1);
        atomicAdd(&den[nhi * NFR + kglob], d1);
      }
    }
  }
}

// ---------------- K3: per-row stats (also zeroes out for loss_k) ----------------
__global__ __launch_bounds__(64) void rowstats_k(const float* __restrict__ num,
                                                 const float* __restrict__ den,
                                                 const float* __restrict__ negnum,
                                                 const float* __restrict__ negden,
                                                 float* __restrict__ Pi_d,
                                                 float* __restrict__ Ni_d,
                                                 float* __restrict__ out) {
  const int r = blockIdx.x;
  const int l = threadIdx.x;
  if (r == 0 && l == 0) out[0] = 0.f;
  float vsum = 0.f, pvac = 0.f;
#pragma unroll
  for (int cb = 0; cb < 4; ++cb) {
    const int k = cb * 64 + l;
    const float ratio = num[r * NFR + k] / den[r * NFR + k];
    vsum += ratio;
    if (k == r) pvac = ratio;
  }
#pragma unroll
  for (int m = 1; m < 64; m <<= 1) {
    vsum += __shfl_xor(vsum, m);
    pvac += __shfl_xor(pvac, m);
  }
  if (l == 0) {
    const float nh = negnum[r] / negden[r];
    Pi_d[r] = TEMP * pvac;
    Ni_d[r] = TEMP * (nh + vsum - 100.f * pvac);   // masked easy-sum
  }
}

// ---------------- K4: loss = (1/N) sum_{i,j} softplus(Ni_d[j]-Pi_d[i]) ---------
__global__ __launch_bounds__(256) void loss_k(const float* __restrict__ Pi_d,
                                              const float* __restrict__ Ni_d,
                                              float* __restrict__ out) {
  __shared__ float red[4];
  const int i = blockIdx.x;
  const int tid = threadIdx.x;
  const int l = tid & 63, w = tid >> 6;
  const float x = Ni_d[tid] - Pi_d[i];
  const float m = fmaxf(x, 0.f);
  float sp = m + __logf(__expf(x - m) + __expf(-m));
#pragma unroll
  for (int s2 = 1; s2 < 64; s2 <<= 1) sp += __shfl_xor(sp, s2);
  if (l == 0) red[w] = sp;
  __syncthreads();
  if (tid == 0) atomicAdd(out, (red[0] + red[1] + red[2] + red[3]) * (1.0f / (float)NFR));
}

extern "C" void kernel_launch(void* const* d_in, const int* in_sizes, int n_in,
                              void* d_out, int out_size, void* d_ws, size_t ws_size,
                              hipStream_t stream) {
  const float* frame = (const float*)d_in[0];   // (256,14,14,512) f32
  const float* audio = (const float*)d_in[1];   // (256,512) f32
  float* out = (float*)d_out;                   // scalar f32

  char* ws = (char*)d_ws;
  unsigned short* abf = (unsigned short*)ws;        // 256 KB
  float* num    = (float*)(ws + 262144);            // num,den,negnum,negden contiguous
  float* den    = num + NFR * NFR;
  float* negnum = den + NFR * NFR;
  float* negden = negnum + NFR;
  float* Pi_d   = negden + NFR;
  float* Ni_d   = Pi_d + NFR;

  audio_norm_k<<<256, 64, 0, stream>>>(audio, abf, num, negnum);
  simk<<<784, 256, 0, stream>>>(frame, abf, num, den, negnum, negden);
  rowstats_k<<<256, 64, 0, stream>>>(num, den, negnum, negden, Pi_d, Ni_d, out);
  loss_k<<<256, 256, 0, stream>>>(Pi_d, Ni_d, out);
}